// Round 6
// baseline (268.023 us; speedup 1.0000x reference)
//
#include <hip/hip_runtime.h>
#include <hip/hip_bf16.h>

#define B_  4
#define L_  4096
#define DM  1024
#define DH  128
#define KS  8     // k-split for pv
#define QS  8     // q-split for stats

// (1/sqrt(128)) * log2(e): softmax computed in exp2 domain (exact same function)
#define SC2 0.12752844f

typedef __bf16 bf16_t;
typedef __attribute__((ext_vector_type(8))) __bf16 bf16x8;
typedef __attribute__((ext_vector_type(4))) __bf16 bf16x4;
typedef __attribute__((ext_vector_type(4))) float f32x4;

#if __has_builtin(__builtin_amdgcn_exp2f)
#define EXP2F(x) __builtin_amdgcn_exp2f(x)
#else
#define EXP2F(x) exp2f(x)
#endif

__device__ __forceinline__ f32x4 mfma16(bf16x8 a, bf16x8 b, f32x4 c) {
    return __builtin_amdgcn_mfma_f32_16x16x32_bf16(a, b, c, 0, 0, 0);
}

// XOR swizzle on 16B slots within a row (row bytes must be 128 or 256)
__device__ __forceinline__ int swz(int row, int rowbytes, int colbyte) {
    int slot = colbyte >> 4;
    return row * rowbytes + (((slot ^ (row & 7)) << 4) | (colbyte & 15));
}

// ---------------------------------------------------------------------------
// Kernel A0: W fp32 -> bf16 once.  Wb layout [3][DH][DM].  grid 192, block 256
// ---------------------------------------------------------------------------
__global__ __launch_bounds__(256) void wcvt_kernel(
    const float* __restrict__ Wq, const float* __restrict__ Wk, const float* __restrict__ Wv,
    bf16_t* __restrict__ Wb)
{
    int idx = (blockIdx.x * 256 + threadIdx.x) * 8;    // into [3][131072]
    int which = idx >> 17;
    int rem = idx & 131071;
    const float* W = which == 0 ? Wq : (which == 1 ? Wk : Wv);
    float4 a = *(const float4*)&W[rem];
    float4 b = *(const float4*)&W[rem + 4];
    bf16x8 o;
    o[0] = (__bf16)a.x; o[1] = (__bf16)a.y; o[2] = (__bf16)a.z; o[3] = (__bf16)a.w;
    o[4] = (__bf16)b.x; o[5] = (__bf16)b.y; o[6] = (__bf16)b.z; o[7] = (__bf16)b.w;
    *(bf16x8*)&Wb[idx] = o;
}

// ---------------------------------------------------------------------------
// Kernel A: projection partials.  grid (256, 3, 4), block 256.
// BM=64, BN=128, K-chunk=256 (kz = blockIdx.z).  3072 blocks -> ~20 waves/CU.
// X staged once to bf16 LDS (contiguous 1-KB row reads); ONE barrier total;
// W fragments read directly from L2 (bf16 Wb); fp32 atomicAdd partial output.
// ---------------------------------------------------------------------------
__global__ __launch_bounds__(256) void projk_kernel(
    const float* __restrict__ Xq, const float* __restrict__ Xk, const float* __restrict__ Xv,
    const bf16_t* __restrict__ Wb,
    float* __restrict__ Qf, float* __restrict__ Kf, float* __restrict__ Vf)
{
    const int which = blockIdx.y;
    const float* X = which == 0 ? Xq : (which == 1 ? Xk : Xv);
    float*       Of = which == 0 ? Qf : (which == 1 ? Kf : Vf);
    const bf16_t* Wm = Wb + (size_t)which * DH * DM;

    __shared__ bf16_t Xlds[64 * 256];      // 32 KB, rows 512 B = 32 slots of 16 B

    const int tid  = threadIdx.x;
    const int lane = tid & 63;
    const int wave = tid >> 6;
    const int wm = wave >> 1, wn = wave & 1;   // 2x2 wave grid: 32m x 64h each
    const int i16 = lane & 15, g4 = lane >> 4;
    const int l5  = lane >> 5, c32 = lane & 31;
    const int row0 = blockIdx.x * 64;
    const int kz   = blockIdx.z;

    // stage X [64 rows][256 f32->bf16]: per wave-issue 2 rows x 1 KB contiguous
    #pragma unroll
    for (int p = 0; p < 8; ++p) {
        int r = wave * 16 + p * 2 + l5;
        const float* g = &X[(size_t)(row0 + r) * DM + kz * 256 + c32 * 8];
        float4 a = *(const float4*)g;
        float4 b = *(const float4*)(g + 4);
        bf16x8 v;
        v[0] = (__bf16)a.x; v[1] = (__bf16)a.y; v[2] = (__bf16)a.z; v[3] = (__bf16)a.w;
        v[4] = (__bf16)b.x; v[5] = (__bf16)b.y; v[6] = (__bf16)b.z; v[7] = (__bf16)b.w;
        *(bf16x8*)((char*)Xlds + r * 512 + ((c32 ^ (r & 7)) << 4)) = v;
    }
    __syncthreads();

    f32x4 acc[2][4] = {};
    #pragma unroll
    for (int j = 0; j < 4; ++j) {
        #pragma unroll
        for (int ks = 0; ks < 2; ++ks) {
            int q = (j * 2 + ks) * 4 + g4;     // global 16B-slot in Xlds row
            bf16x8 af[2], bfr[4];
            #pragma unroll
            for (int mi = 0; mi < 2; ++mi) {
                int r = wm * 32 + mi * 16 + i16;
                af[mi] = *(const bf16x8*)((const char*)Xlds + r * 512 + ((q ^ (r & 7)) << 4));
            }
            #pragma unroll
            for (int ni = 0; ni < 4; ++ni) {
                int rw = wn * 64 + ni * 16 + i16;
                bfr[ni] = *(const bf16x8*)&Wm[(size_t)rw * DM + kz * 256 + j * 64 + ks * 32 + g4 * 8];
            }
            #pragma unroll
            for (int mi = 0; mi < 2; ++mi)
                #pragma unroll
                for (int ni = 0; ni < 4; ++ni)
                    acc[mi][ni] = mfma16(af[mi], bfr[ni], acc[mi][ni]);
        }
    }

    // epilogue: fp32 atomic partial accumulate (4 kz blocks per output)
    #pragma unroll
    for (int ni = 0; ni < 4; ++ni) {
        int h = wn * 64 + ni * 16 + i16;
        #pragma unroll
        for (int mi = 0; mi < 2; ++mi)
            #pragma unroll
            for (int jj = 0; jj < 4; ++jj) {
                int r = row0 + wm * 32 + mi * 16 + g4 * 4 + jj;
                atomicAdd(&Of[(size_t)r * DH + h], acc[mi][ni][jj]);
            }
    }
}

// ---------------------------------------------------------------------------
// Kernel A2: Q/K/V = bf16(partial + bias).  grid 3072, block 256 (8 elem/thr)
// ---------------------------------------------------------------------------
__global__ __launch_bounds__(256) void cvtbias_kernel(
    const float* __restrict__ Qf, const float* __restrict__ Kf, const float* __restrict__ Vf,
    const float* __restrict__ bq, const float* __restrict__ bk, const float* __restrict__ bv,
    bf16_t* __restrict__ Q, bf16_t* __restrict__ K, bf16_t* __restrict__ V)
{
    size_t f8 = ((size_t)blockIdx.x * 256 + threadIdx.x) * 8;   // over 3 * 2^21
    int which = (int)(f8 >> 21);
    size_t rem = f8 & ((1u << 21) - 1);
    const float* Of   = which == 0 ? Qf : (which == 1 ? Kf : Vf);
    const float* bias = which == 0 ? bq : (which == 1 ? bk : bv);
    bf16_t*      O    = which == 0 ? Q  : (which == 1 ? K  : V);
    int h0 = (int)(rem & 127);
    float4 p0 = *(const float4*)&Of[rem];
    float4 p1 = *(const float4*)&Of[rem + 4];
    float4 b0 = *(const float4*)&bias[h0];
    float4 b1 = *(const float4*)&bias[h0 + 4];
    bf16x8 o;
    o[0] = (__bf16)(p0.x + b0.x); o[1] = (__bf16)(p0.y + b0.y);
    o[2] = (__bf16)(p0.z + b0.z); o[3] = (__bf16)(p0.w + b0.w);
    o[4] = (__bf16)(p1.x + b1.x); o[5] = (__bf16)(p1.y + b1.y);
    o[6] = (__bf16)(p1.z + b1.z); o[7] = (__bf16)(p1.w + b1.w);
    *(bf16x8*)&O[rem] = o;
}

// ---------------------------------------------------------------------------
// Kernel B: column-softmax partial stats over a q-range of L/QS.
// grid (64, B, QS), block 256.  Per block: 64 k-columns, L/QS q rows.
// ---------------------------------------------------------------------------
__global__ __launch_bounds__(256) void stats_kernel(
    const bf16_t* __restrict__ Q, const bf16_t* __restrict__ K,
    float* __restrict__ Mpart, float* __restrict__ Lpart)
{
    const int b  = blockIdx.y;
    const int k0 = blockIdx.x * 64;
    const int qs = blockIdx.z;
    const int tid = threadIdx.x, lane = tid & 63, wave = tid >> 6;

    __shared__ bf16_t Klds[64 * 128];    // 16 KB, rows 256 B swizzled
    __shared__ bf16_t Qlds[128 * 128];   // 32 KB

    const bf16_t* Kb = K + ((size_t)b * L_ + k0) * DH;
    #pragma unroll
    for (int it = 0; it < 4; ++it) {
        int id = it * 256 + tid;
        int r = id >> 4, s = id & 15;
        bf16x8 x = *(const bf16x8*)&Kb[(size_t)r * DH + s * 8];
        *(bf16x8*)((char*)Klds + swz(r, 256, s * 16)) = x;
    }
    __syncthreads();
    // resident K fragments: [ni = 16-col block][d-slice]
    bf16x8 kfr[4][4];
    #pragma unroll
    for (int ni = 0; ni < 4; ++ni)
        #pragma unroll
        for (int ds = 0; ds < 4; ++ds) {
            int r = ni * 16 + (lane & 15);
            kfr[ni][ds] = *(const bf16x8*)((const char*)Klds + swz(r, 256, ds * 64 + (lane >> 4) * 16));
        }

    float mrun[4], lrun[4];
    #pragma unroll
    for (int ni = 0; ni < 4; ++ni) { mrun[ni] = -1e30f; lrun[ni] = 0.f; }

    const bf16_t* Qb = Q + (size_t)b * L_ * DH;
    const int qbase = qs * (L_ / QS);
    for (int q0 = qbase; q0 < qbase + L_ / QS; q0 += 128) {
        __syncthreads();
        #pragma unroll
        for (int it = 0; it < 8; ++it) {
            int id = it * 256 + tid;
            int r = id >> 4, s = id & 15;
            bf16x8 x = *(const bf16x8*)&Qb[(size_t)(q0 + r) * DH + s * 8];
            *(bf16x8*)((char*)Qlds + swz(r, 256, s * 16)) = x;
        }
        __syncthreads();
        // wave w: q rows [w*32, w*32+32), all 64 k
        f32x4 st[2][4] = {};
        #pragma unroll
        for (int mi = 0; mi < 2; ++mi)
            #pragma unroll
            for (int ds = 0; ds < 4; ++ds) {
                int r = wave * 32 + mi * 16 + (lane & 15);
                bf16x8 af = *(const bf16x8*)((const char*)Qlds + swz(r, 256, ds * 64 + (lane >> 4) * 16));
                #pragma unroll
                for (int ni = 0; ni < 4; ++ni)
                    st[mi][ni] = mfma16(af, kfr[ni][ds], st[mi][ni]);
            }
        // online per-column update (col k = lane&15 within ni block)
        #pragma unroll
        for (int ni = 0; ni < 4; ++ni) {
            float cm = -1e30f;
            #pragma unroll
            for (int mi = 0; mi < 2; ++mi)
                #pragma unroll
                for (int j = 0; j < 4; ++j) cm = fmaxf(cm, st[mi][ni][j]);
            cm *= SC2;
            cm = fmaxf(cm, __shfl_xor(cm, 16, 64));
            cm = fmaxf(cm, __shfl_xor(cm, 32, 64));
            float mnew = fmaxf(mrun[ni], cm);
            float p = 0.f;
            #pragma unroll
            for (int mi = 0; mi < 2; ++mi)
                #pragma unroll
                for (int j = 0; j < 4; ++j)
                    p += EXP2F(st[mi][ni][j] * SC2 - mnew);
            p += __shfl_xor(p, 16, 64);
            p += __shfl_xor(p, 32, 64);
            lrun[ni] = lrun[ni] * EXP2F(mrun[ni] - mnew) + p;
            mrun[ni] = mnew;
        }
    }
    // cross-wave combine (each wave covered a disjoint q subset)
    __syncthreads();
    float* redm = (float*)Klds;       // reuse: 4*64 floats
    float* redl = redm + 256;
    if (lane < 16) {
        #pragma unroll
        for (int ni = 0; ni < 4; ++ni) {
            redm[wave * 64 + ni * 16 + lane] = mrun[ni];
            redl[wave * 64 + ni * 16 + lane] = lrun[ni];
        }
    }
    __syncthreads();
    if (tid < 64) {
        float m0 = redm[tid], m1 = redm[64 + tid], m2v = redm[128 + tid], m3 = redm[192 + tid];
        float mt = fmaxf(fmaxf(m0, m1), fmaxf(m2v, m3));
        float lt = redl[tid]       * EXP2F(m0 - mt) + redl[64 + tid]  * EXP2F(m1 - mt)
                 + redl[128 + tid] * EXP2F(m2v - mt) + redl[192 + tid] * EXP2F(m3 - mt);
        Mpart[((size_t)qs * B_ + b) * L_ + k0 + tid] = mt;
        Lpart[((size_t)qs * B_ + b) * L_ + k0 + tid] = lt;
    }
}

// ---------------------------------------------------------------------------
// Kernel B2: combine QS partial stats -> M2, Lsum.  grid (B*L/256), block 256
// ---------------------------------------------------------------------------
__global__ __launch_bounds__(256) void comb_kernel(
    const float* __restrict__ Mpart, const float* __restrict__ Lpart,
    float* __restrict__ M2, float* __restrict__ Lsum)
{
    const size_t i = (size_t)blockIdx.x * 256 + threadIdx.x;
    const size_t N = (size_t)B_ * L_;
    float m = -1e30f;
    #pragma unroll
    for (int qs = 0; qs < QS; ++qs) m = fmaxf(m, Mpart[qs * N + i]);
    float l = 0.f;
    #pragma unroll
    for (int qs = 0; qs < QS; ++qs) l += Lpart[qs * N + i] * EXP2F(Mpart[qs * N + i] - m);
    M2[i] = m;
    Lsum[i] = l;
}

// ---------------------------------------------------------------------------
// Kernel C: VT[b][v][k] = V[b][k][v] / l[b][k]   (transpose + scale)
// grid (64, 2, 4), block 256
// ---------------------------------------------------------------------------
__global__ __launch_bounds__(256) void vt_kernel(
    const bf16_t* __restrict__ V, const float* __restrict__ Lsum, bf16_t* __restrict__ VT)
{
    const int b = blockIdx.z, v0 = blockIdx.y * 64, k0 = blockIdx.x * 64;
    __shared__ bf16_t tile[64][72];
    const int tid = threadIdx.x;
    const bf16_t* Vb = V + ((size_t)b * L_ + k0) * DH + v0;
    #pragma unroll
    for (int it = 0; it < 2; ++it) {
        int id = it * 256 + tid;
        int r = id >> 3, s = id & 7;
        bf16x8 x = *(const bf16x8*)&Vb[(size_t)r * DH + s * 8];
        *(bf16x8*)&tile[r][s * 8] = x;
    }
    __syncthreads();
    const int lane = tid & 63, wave = tid >> 6;
    float rl = 1.0f / Lsum[(size_t)b * L_ + k0 + lane];
    bf16_t* VTb = VT + ((size_t)b * DH + v0) * L_ + k0;
    #pragma unroll
    for (int i = 0; i < 16; ++i) {
        int v = wave * 16 + i;
        float x = (float)tile[lane][v];
        VTb[(size_t)v * L_ + lane] = (__bf16)(x * rl);
    }
}

// ---------------------------------------------------------------------------
// Kernel D: H[q,v] += sum_{k in range} exp2(s*SC2 - m2[k]) * VT[v][k]
// grid (64, B, KS), block 256 (4 waves).  q-block 64, k-range L/KS, chunks 64.
// Partial k-sums are additive (1/l folded into VT) -> fp32 atomicAdd to out.
// ---------------------------------------------------------------------------
__global__ __launch_bounds__(256) void pv_kernel(
    const bf16_t* __restrict__ Q, const bf16_t* __restrict__ K,
    const bf16_t* __restrict__ VT, const float* __restrict__ M2,
    float* __restrict__ out)
{
    const int b = blockIdx.y;
    const int q0 = blockIdx.x * 64;
    const int tid = threadIdx.x, lane = tid & 63, wave = tid >> 6;

    __shared__ bf16_t QPlds[64 * 128];   // 16 KB: Q staging, then P tile (first 8 KB)
    __shared__ bf16_t Klds[64 * 128];    // 16 KB
    __shared__ bf16_t VTlds[128 * 64];   // 16 KB, rows 128 B

    const bf16_t* Qb = Q + ((size_t)b * L_ + q0) * DH;
    #pragma unroll
    for (int it = 0; it < 4; ++it) {
        int id = it * 256 + tid;
        int r = id >> 4, s = id & 15;
        bf16x8 x = *(const bf16x8*)&Qb[(size_t)r * DH + s * 8];
        *(bf16x8*)((char*)QPlds + swz(r, 256, s * 16)) = x;
    }
    __syncthreads();
    // resident Q fragments (B-operand of S^T): [ni = q 16-block][d-slice]
    bf16x8 qf[4][4];
    #pragma unroll
    for (int ni = 0; ni < 4; ++ni)
        #pragma unroll
        for (int ds = 0; ds < 4; ++ds) {
            int r = ni * 16 + (lane & 15);
            qf[ni][ds] = *(const bf16x8*)((const char*)QPlds + swz(r, 256, ds * 64 + (lane >> 4) * 16));
        }

    f32x4 acc[4][2] = {};
    const float*  m2b = M2 + (size_t)b * L_;
    const bf16_t* Kb  = K  + (size_t)b * L_ * DH;
    const bf16_t* VTb = VT + (size_t)b * DH * L_;
    bf16_t* Plds = QPlds;                // alias: safe after qf loads + barrier

    const int kbase = blockIdx.z * (L_ / KS);
    for (int kc = kbase; kc < kbase + L_ / KS; kc += 64) {
        __syncthreads();
        // stage K chunk [64 k][128 d]
        #pragma unroll
        for (int it = 0; it < 4; ++it) {
            int id = it * 256 + tid;
            int r = id >> 4, s = id & 15;
            bf16x8 x = *(const bf16x8*)&Kb[(size_t)(kc + r) * DH + s * 8];
            *(bf16x8*)((char*)Klds + swz(r, 256, s * 16)) = x;
        }
        // stage VT chunk [128 v][64 k]
        #pragma unroll
        for (int it = 0; it < 4; ++it) {
            int id = it * 256 + tid;
            int r = id >> 3, s = id & 7;
            bf16x8 x = *(const bf16x8*)&VTb[(size_t)r * L_ + kc + s * 8];
            *(bf16x8*)((char*)VTlds + swz(r, 128, s * 16)) = x;
        }
        __syncthreads();
        // S^T tile: wave w owns k rows [w*16, w*16+16), all 64 q
        f32x4 st[4] = {};
        #pragma unroll
        for (int ds = 0; ds < 4; ++ds) {
            int r = wave * 16 + (lane & 15);
            bf16x8 kf = *(const bf16x8*)((const char*)Klds + swz(r, 256, ds * 64 + (lane >> 4) * 16));
            #pragma unroll
            for (int ni = 0; ni < 4; ++ni)
                st[ni] = mfma16(kf, qf[ni][ds], st[ni]);
        }
        // P = exp2(s*SC2 - m2[k]), write bf16 to Plds (lane's 4 k contiguous)
        float4 mv = *(const float4*)&m2b[kc + wave * 16 + (lane >> 4) * 4];
        #pragma unroll
        for (int ni = 0; ni < 4; ++ni) {
            bf16x4 pk;
            pk[0] = (__bf16)EXP2F(st[ni][0] * SC2 - mv.x);
            pk[1] = (__bf16)EXP2F(st[ni][1] * SC2 - mv.y);
            pk[2] = (__bf16)EXP2F(st[ni][2] * SC2 - mv.z);
            pk[3] = (__bf16)EXP2F(st[ni][3] * SC2 - mv.w);
            int q = ni * 16 + (lane & 15);
            int colbyte = wave * 32 + (lane >> 4) * 8;
            *(bf16x4*)((char*)Plds + swz(q, 128, colbyte)) = pk;
        }
        __syncthreads();
        // PV: wave w owns v strip [w*32, w*32+32)
        #pragma unroll
        for (int ks = 0; ks < 2; ++ks) {
            bf16x8 pf[4], vf[2];
            #pragma unroll
            for (int mi = 0; mi < 4; ++mi) {
                int q = mi * 16 + (lane & 15);
                pf[mi] = *(const bf16x8*)((const char*)Plds + swz(q, 128, ks * 64 + (lane >> 4) * 16));
            }
            #pragma unroll
            for (int ni = 0; ni < 2; ++ni) {
                int v = wave * 32 + ni * 16 + (lane & 15);
                vf[ni] = *(const bf16x8*)((const char*)VTlds + swz(v, 128, ks * 64 + (lane >> 4) * 16));
            }
            #pragma unroll
            for (int mi = 0; mi < 4; ++mi)
                #pragma unroll
                for (int ni = 0; ni < 2; ++ni)
                    acc[mi][ni] = mfma16(pf[mi], vf[ni], acc[mi][ni]);
        }
    }
    // epilogue: fp32 atomic accumulate (KS blocks contribute per output)
    #pragma unroll
    for (int mi = 0; mi < 4; ++mi)
        #pragma unroll
        for (int ni = 0; ni < 2; ++ni)
            #pragma unroll
            for (int j = 0; j < 4; ++j) {
                int q = q0 + mi * 16 + (lane >> 4) * 4 + j;
                int v = wave * 32 + ni * 16 + (lane & 15);
                atomicAdd(&out[((size_t)b * L_ + q) * DH + v], acc[mi][ni][j]);
            }
}

// ---------------------------------------------------------------------------
extern "C" void kernel_launch(void* const* d_in, const int* in_sizes, int n_in,
                              void* d_out, int out_size, void* d_ws, size_t ws_size,
                              hipStream_t stream)
{
    const float* inq = (const float*)d_in[0];
    const float* ink = (const float*)d_in[1];
    const float* inv = (const float*)d_in[2];
    const float* Wq  = (const float*)d_in[3];
    const float* bq  = (const float*)d_in[4];
    const float* Wk  = (const float*)d_in[5];
    const float* bk  = (const float*)d_in[6];
    const float* Wv  = (const float*)d_in[7];
    const float* bv  = (const float*)d_in[8];
    float* out = (float*)d_out;

    const size_t nQKV = (size_t)B_ * L_ * DH;   // 2,097,152 elements
    const size_t nBL  = (size_t)B_ * L_;
    char* ws = (char*)d_ws;
    bf16_t* Q  = (bf16_t*)ws;
    bf16_t* K  = Q + nQKV;
    bf16_t* V  = K + nQKV;
    bf16_t* VT = V + nQKV;
    float*  M2    = (float*)(VT + nQKV);
    float*  Lsum  = M2 + nBL;
    float*  Mpart = Lsum + nBL;          // QS * B*L
    float*  Lpart = Mpart + QS * nBL;    // QS * B*L
    float*  Qf    = Lpart + QS * nBL;    // 3 x nQKV fp32 projection partials
    float*  Kf    = Qf + nQKV;
    float*  Vf    = Kf + nQKV;
    // Wb (3*128*1024 bf16 = 768 KB) aliases the VT region: Wb is only live
    // during wcvt+projk; VT is written by vt_kernel strictly after.
    bf16_t* Wbuf = VT;

    hipMemsetAsync(out, 0, nQKV * sizeof(float), stream);
    hipMemsetAsync(Qf, 0, 3 * nQKV * sizeof(float), stream);
    wcvt_kernel<<<dim3(192), 256, 0, stream>>>(Wq, Wk, Wv, Wbuf);
    projk_kernel<<<dim3(256, 3, 4), 256, 0, stream>>>(inq, ink, inv, Wbuf, Qf, Kf, Vf);
    cvtbias_kernel<<<dim3(3072), 256, 0, stream>>>(Qf, Kf, Vf, bq, bk, bv, Q, K, V);
    stats_kernel<<<dim3(L_ / 64, B_, QS), 256, 0, stream>>>(Q, K, Mpart, Lpart);
    comb_kernel<<<dim3(nBL / 256), 256, 0, stream>>>(Mpart, Lpart, M2, Lsum);
    vt_kernel<<<dim3(L_ / 64, DH / 64, B_), 256, 0, stream>>>(V, Lsum, VT);
    pv_kernel<<<dim3(L_ / 64, B_, KS), 256, 0, stream>>>(Q, K, VT, M2, out);
}

// Round 8
// 263.411 us; speedup vs baseline: 1.0175x; 1.0175x over previous
//
#include <hip/hip_runtime.h>
#include <hip/hip_bf16.h>

#define B_  4
#define L_  4096
#define DM  1024
#define DH  128
#define KS  8     // k-split for pv
#define QS  8     // q-split for stats

// (1/sqrt(128)) * log2(e): softmax computed in exp2 domain (exact same function)
#define SC2 0.12752844f

typedef __bf16 bf16_t;
typedef __attribute__((ext_vector_type(8))) __bf16 bf16x8;
typedef __attribute__((ext_vector_type(4))) __bf16 bf16x4;
typedef __attribute__((ext_vector_type(4))) float f32x4;

#if __has_builtin(__builtin_amdgcn_exp2f)
#define EXP2F(x) __builtin_amdgcn_exp2f(x)
#else
#define EXP2F(x) exp2f(x)
#endif

__device__ __forceinline__ f32x4 mfma16(bf16x8 a, bf16x8 b, f32x4 c) {
    return __builtin_amdgcn_mfma_f32_16x16x32_bf16(a, b, c, 0, 0, 0);
}

// XOR swizzle on 16B slots within a row (row bytes must be 128 or 256)
__device__ __forceinline__ int swz(int row, int rowbytes, int colbyte) {
    int slot = colbyte >> 4;
    return row * rowbytes + (((slot ^ (row & 7)) << 4) | (colbyte & 15));
}

__device__ __forceinline__ bf16x8 cvt8v(f32x4 a, f32x4 b) {
    bf16x8 v;
    v[0] = (__bf16)a.x; v[1] = (__bf16)a.y; v[2] = (__bf16)a.z; v[3] = (__bf16)a.w;
    v[4] = (__bf16)b.x; v[5] = (__bf16)b.y; v[6] = (__bf16)b.z; v[7] = (__bf16)b.w;
    return v;
}

// ---------------------------------------------------------------------------
// Kernel A0: W fp32 -> bf16 once.  Wb layout [3][DH][DM].  grid 192, block 256
// ---------------------------------------------------------------------------
__global__ __launch_bounds__(256) void wcvt_kernel(
    const float* __restrict__ Wq, const float* __restrict__ Wk, const float* __restrict__ Wv,
    bf16_t* __restrict__ Wb)
{
    int idx = (blockIdx.x * 256 + threadIdx.x) * 8;    // into [3][131072]
    int which = idx >> 17;
    int rem = idx & 131071;
    const float* W = which == 0 ? Wq : (which == 1 ? Wk : Wv);
    f32x4 a = *(const f32x4*)&W[rem];
    f32x4 b = *(const f32x4*)&W[rem + 4];
    *(bf16x8*)&Wb[idx] = cvt8v(a, b);
}

// ---------------------------------------------------------------------------
// Kernel A: direct projections, NO LDS, NO barriers.
// grid (512, 3), block 128 (2 waves).  Each wave owns 16 rows x full K.
// A-frag loaded straight from global fp32 (nontemporal, each line read once),
// cvt to bf16 in regs; B-frag (bf16 W) from L2.  2-deep software pipeline with
// NAMED buffers.  Every wave issues loads continuously -> streaming-rate HBM.
// ---------------------------------------------------------------------------
__global__ __launch_bounds__(128) void projd_kernel(
    const float* __restrict__ Xq, const float* __restrict__ Xk, const float* __restrict__ Xv,
    const bf16_t* __restrict__ Wb,
    const float* __restrict__ bq, const float* __restrict__ bk, const float* __restrict__ bv,
    bf16_t* __restrict__ Q, bf16_t* __restrict__ K, bf16_t* __restrict__ V)
{
    const int which = blockIdx.y;
    const float* X    = which == 0 ? Xq : (which == 1 ? Xk : Xv);
    const float* bias = which == 0 ? bq : (which == 1 ? bk : bv);
    bf16_t*      O    = which == 0 ? Q  : (which == 1 ? K  : V);
    const bf16_t* Wm  = Wb + (size_t)which * DH * DM;

    const int lane = threadIdx.x & 63;
    const int wave = threadIdx.x >> 6;
    const int i16 = lane & 15, g4 = lane >> 4;
    const int mbase = blockIdx.x * 32 + wave * 16;

    // lane's A-row pointer (row = mbase+i16, k-offset = s*32 + g4*8)
    const float*  xp = X  + (size_t)(mbase + i16) * DM + g4 * 8;
    // lane's B-col pointer (h = ni*16+i16, same k-offset)
    const bf16_t* wp = Wm + (size_t)i16 * DM + g4 * 8;

    f32x4 acc[8] = {};

    // prologue: load step 0 into buffer A
    f32x4 xaA = __builtin_nontemporal_load((const f32x4*)xp);
    f32x4 xbA = __builtin_nontemporal_load((const f32x4*)(xp + 4));
    bf16x8 wA[8];
    #pragma unroll
    for (int ni = 0; ni < 8; ++ni)
        wA[ni] = *(const bf16x8*)(wp + (size_t)ni * 16 * DM);

    f32x4 xaB, xbB;
    bf16x8 wB[8];

    for (int s = 0; s < 32; s += 2) {
        // prefetch step s+1 into B (s+1 <= 31 always)
        {
            const float*  xn = xp + (s + 1) * 32;
            const bf16_t* wn_ = wp + (s + 1) * 32;
            xaB = __builtin_nontemporal_load((const f32x4*)xn);
            xbB = __builtin_nontemporal_load((const f32x4*)(xn + 4));
            #pragma unroll
            for (int ni = 0; ni < 8; ++ni)
                wB[ni] = *(const bf16x8*)(wn_ + (size_t)ni * 16 * DM);
        }
        // compute step s from A
        {
            bf16x8 af = cvt8v(xaA, xbA);
            #pragma unroll
            for (int ni = 0; ni < 8; ++ni)
                acc[ni] = mfma16(af, wA[ni], acc[ni]);
        }
        // prefetch step s+2 into A
        if (s + 2 < 32) {
            const float*  xn = xp + (s + 2) * 32;
            const bf16_t* wn_ = wp + (s + 2) * 32;
            xaA = __builtin_nontemporal_load((const f32x4*)xn);
            xbA = __builtin_nontemporal_load((const f32x4*)(xn + 4));
            #pragma unroll
            for (int ni = 0; ni < 8; ++ni)
                wA[ni] = *(const bf16x8*)(wn_ + (size_t)ni * 16 * DM);
        }
        // compute step s+1 from B
        {
            bf16x8 af = cvt8v(xaB, xbB);
            #pragma unroll
            for (int ni = 0; ni < 8; ++ni)
                acc[ni] = mfma16(af, wB[ni], acc[ni]);
        }
    }

    // epilogue: + bias, write bf16.  C/D: col=lane&15, row=(lane>>4)*4+j
    #pragma unroll
    for (int ni = 0; ni < 8; ++ni) {
        float bb = bias[ni * 16 + i16];
        #pragma unroll
        for (int j = 0; j < 4; ++j) {
            int r = mbase + g4 * 4 + j;
            O[(size_t)r * DH + ni * 16 + i16] = (__bf16)(acc[ni][j] + bb);
        }
    }
}

// ---------------------------------------------------------------------------
// Kernel B: column-softmax partial stats over a q-range of L/QS.
// grid (64, B, QS), block 256.  Per block: 64 k-columns, L/QS q rows.
// ---------------------------------------------------------------------------
__global__ __launch_bounds__(256) void stats_kernel(
    const bf16_t* __restrict__ Q, const bf16_t* __restrict__ K,
    float* __restrict__ Mpart, float* __restrict__ Lpart)
{
    const int b  = blockIdx.y;
    const int k0 = blockIdx.x * 64;
    const int qs = blockIdx.z;
    const int tid = threadIdx.x, lane = tid & 63, wave = tid >> 6;

    __shared__ bf16_t Klds[64 * 128];    // 16 KB, rows 256 B swizzled
    __shared__ bf16_t Qlds[128 * 128];   // 32 KB

    const bf16_t* Kb = K + ((size_t)b * L_ + k0) * DH;
    #pragma unroll
    for (int it = 0; it < 4; ++it) {
        int id = it * 256 + tid;
        int r = id >> 4, s = id & 15;
        bf16x8 x = *(const bf16x8*)&Kb[(size_t)r * DH + s * 8];
        *(bf16x8*)((char*)Klds + swz(r, 256, s * 16)) = x;
    }
    __syncthreads();
    // resident K fragments: [ni = 16-col block][d-slice]
    bf16x8 kfr[4][4];
    #pragma unroll
    for (int ni = 0; ni < 4; ++ni)
        #pragma unroll
        for (int ds = 0; ds < 4; ++ds) {
            int r = ni * 16 + (lane & 15);
            kfr[ni][ds] = *(const bf16x8*)((const char*)Klds + swz(r, 256, ds * 64 + (lane >> 4) * 16));
        }

    float mrun[4], lrun[4];
    #pragma unroll
    for (int ni = 0; ni < 4; ++ni) { mrun[ni] = -1e30f; lrun[ni] = 0.f; }

    const bf16_t* Qb = Q + (size_t)b * L_ * DH;
    const int qbase = qs * (L_ / QS);
    for (int q0 = qbase; q0 < qbase + L_ / QS; q0 += 128) {
        __syncthreads();
        #pragma unroll
        for (int it = 0; it < 8; ++it) {
            int id = it * 256 + tid;
            int r = id >> 4, s = id & 15;
            bf16x8 x = *(const bf16x8*)&Qb[(size_t)(q0 + r) * DH + s * 8];
            *(bf16x8*)((char*)Qlds + swz(r, 256, s * 16)) = x;
        }
        __syncthreads();
        // wave w: q rows [w*32, w*32+32), all 64 k
        f32x4 st[2][4] = {};
        #pragma unroll
        for (int mi = 0; mi < 2; ++mi)
            #pragma unroll
            for (int ds = 0; ds < 4; ++ds) {
                int r = wave * 32 + mi * 16 + (lane & 15);
                bf16x8 af = *(const bf16x8*)((const char*)Qlds + swz(r, 256, ds * 64 + (lane >> 4) * 16));
                #pragma unroll
                for (int ni = 0; ni < 4; ++ni)
                    st[mi][ni] = mfma16(af, kfr[ni][ds], st[mi][ni]);
            }
        // online per-column update (col k = lane&15 within ni block)
        #pragma unroll
        for (int ni = 0; ni < 4; ++ni) {
            float cm = -1e30f;
            #pragma unroll
            for (int mi = 0; mi < 2; ++mi)
                #pragma unroll
                for (int j = 0; j < 4; ++j) cm = fmaxf(cm, st[mi][ni][j]);
            cm *= SC2;
            cm = fmaxf(cm, __shfl_xor(cm, 16, 64));
            cm = fmaxf(cm, __shfl_xor(cm, 32, 64));
            float mnew = fmaxf(mrun[ni], cm);
            float p = 0.f;
            #pragma unroll
            for (int mi = 0; mi < 2; ++mi)
                #pragma unroll
                for (int j = 0; j < 4; ++j)
                    p += EXP2F(st[mi][ni][j] * SC2 - mnew);
            p += __shfl_xor(p, 16, 64);
            p += __shfl_xor(p, 32, 64);
            lrun[ni] = lrun[ni] * EXP2F(mrun[ni] - mnew) + p;
            mrun[ni] = mnew;
        }
    }
    // cross-wave combine (each wave covered a disjoint q subset)
    __syncthreads();
    float* redm = (float*)Klds;       // reuse: 4*64 floats
    float* redl = redm + 256;
    if (lane < 16) {
        #pragma unroll
        for (int ni = 0; ni < 4; ++ni) {
            redm[wave * 64 + ni * 16 + lane] = mrun[ni];
            redl[wave * 64 + ni * 16 + lane] = lrun[ni];
        }
    }
    __syncthreads();
    if (tid < 64) {
        float m0 = redm[tid], m1 = redm[64 + tid], m2v = redm[128 + tid], m3 = redm[192 + tid];
        float mt = fmaxf(fmaxf(m0, m1), fmaxf(m2v, m3));
        float lt = redl[tid]       * EXP2F(m0 - mt) + redl[64 + tid]  * EXP2F(m1 - mt)
                 + redl[128 + tid] * EXP2F(m2v - mt) + redl[192 + tid] * EXP2F(m3 - mt);
        Mpart[((size_t)qs * B_ + b) * L_ + k0 + tid] = mt;
        Lpart[((size_t)qs * B_ + b) * L_ + k0 + tid] = lt;
    }
}

// ---------------------------------------------------------------------------
// Kernel B2: combine QS partial stats -> M2, Lsum.  grid (B*L/256), block 256
// ---------------------------------------------------------------------------
__global__ __launch_bounds__(256) void comb_kernel(
    const float* __restrict__ Mpart, const float* __restrict__ Lpart,
    float* __restrict__ M2, float* __restrict__ Lsum)
{
    const size_t i = (size_t)blockIdx.x * 256 + threadIdx.x;
    const size_t N = (size_t)B_ * L_;
    float m = -1e30f;
    #pragma unroll
    for (int qs = 0; qs < QS; ++qs) m = fmaxf(m, Mpart[qs * N + i]);
    float l = 0.f;
    #pragma unroll
    for (int qs = 0; qs < QS; ++qs) l += Lpart[qs * N + i] * EXP2F(Mpart[qs * N + i] - m);
    M2[i] = m;
    Lsum[i] = l;
}

// ---------------------------------------------------------------------------
// Kernel C: VT[b][v][k] = V[b][k][v] / l[b][k]   (transpose + scale)
// grid (64, 2, 4), block 256
// ---------------------------------------------------------------------------
__global__ __launch_bounds__(256) void vt_kernel(
    const bf16_t* __restrict__ V, const float* __restrict__ Lsum, bf16_t* __restrict__ VT)
{
    const int b = blockIdx.z, v0 = blockIdx.y * 64, k0 = blockIdx.x * 64;
    __shared__ bf16_t tile[64][72];
    const int tid = threadIdx.x;
    const bf16_t* Vb = V + ((size_t)b * L_ + k0) * DH + v0;
    #pragma unroll
    for (int it = 0; it < 2; ++it) {
        int id = it * 256 + tid;
        int r = id >> 3, s = id & 7;
        bf16x8 x = *(const bf16x8*)&Vb[(size_t)r * DH + s * 8];
        *(bf16x8*)&tile[r][s * 8] = x;
    }
    __syncthreads();
    const int lane = tid & 63, wave = tid >> 6;
    float rl = 1.0f / Lsum[(size_t)b * L_ + k0 + lane];
    bf16_t* VTb = VT + ((size_t)b * DH + v0) * L_ + k0;
    #pragma unroll
    for (int i = 0; i < 16; ++i) {
        int v = wave * 16 + i;
        float x = (float)tile[lane][v];
        VTb[(size_t)v * L_ + lane] = (__bf16)(x * rl);
    }
}

// ---------------------------------------------------------------------------
// Kernel D: H[q,v] += sum_{k in range} exp2(s*SC2 - m2[k]) * VT[v][k]
// grid (64, B, KS), block 256 (4 waves).  q-block 64, k-range L/KS, chunks 64.
// Partial k-sums are additive (1/l folded into VT) -> fp32 atomicAdd to out.
// ---------------------------------------------------------------------------
__global__ __launch_bounds__(256) void pv_kernel(
    const bf16_t* __restrict__ Q, const bf16_t* __restrict__ K,
    const bf16_t* __restrict__ VT, const float* __restrict__ M2,
    float* __restrict__ out)
{
    const int b = blockIdx.y;
    const int q0 = blockIdx.x * 64;
    const int tid = threadIdx.x, lane = tid & 63, wave = tid >> 6;

    __shared__ bf16_t QPlds[64 * 128];   // 16 KB: Q staging, then P tile (first 8 KB)
    __shared__ bf16_t Klds[64 * 128];    // 16 KB
    __shared__ bf16_t VTlds[128 * 64];   // 16 KB, rows 128 B

    const bf16_t* Qb = Q + ((size_t)b * L_ + q0) * DH;
    #pragma unroll
    for (int it = 0; it < 4; ++it) {
        int id = it * 256 + tid;
        int r = id >> 4, s = id & 15;
        bf16x8 x = *(const bf16x8*)&Qb[(size_t)r * DH + s * 8];
        *(bf16x8*)((char*)QPlds + swz(r, 256, s * 16)) = x;
    }
    __syncthreads();
    // resident Q fragments (B-operand of S^T): [ni = q 16-block][d-slice]
    bf16x8 qf[4][4];
    #pragma unroll
    for (int ni = 0; ni < 4; ++ni)
        #pragma unroll
        for (int ds = 0; ds < 4; ++ds) {
            int r = ni * 16 + (lane & 15);
            qf[ni][ds] = *(const bf16x8*)((const char*)QPlds + swz(r, 256, ds * 64 + (lane >> 4) * 16));
        }

    f32x4 acc[4][2] = {};
    const float*  m2b = M2 + (size_t)b * L_;
    const bf16_t* Kb  = K  + (size_t)b * L_ * DH;
    const bf16_t* VTb = VT + (size_t)b * DH * L_;
    bf16_t* Plds = QPlds;                // alias: safe after qf loads + barrier

    const int kbase = blockIdx.z * (L_ / KS);
    for (int kc = kbase; kc < kbase + L_ / KS; kc += 64) {
        __syncthreads();
        // stage K chunk [64 k][128 d]
        #pragma unroll
        for (int it = 0; it < 4; ++it) {
            int id = it * 256 + tid;
            int r = id >> 4, s = id & 15;
            bf16x8 x = *(const bf16x8*)&Kb[(size_t)(kc + r) * DH + s * 8];
            *(bf16x8*)((char*)Klds + swz(r, 256, s * 16)) = x;
        }
        // stage VT chunk [128 v][64 k]
        #pragma unroll
        for (int it = 0; it < 4; ++it) {
            int id = it * 256 + tid;
            int r = id >> 3, s = id & 7;
            bf16x8 x = *(const bf16x8*)&VTb[(size_t)r * L_ + kc + s * 8];
            *(bf16x8*)((char*)VTlds + swz(r, 128, s * 16)) = x;
        }
        __syncthreads();
        // S^T tile: wave w owns k rows [w*16, w*16+16), all 64 q
        f32x4 st[4] = {};
        #pragma unroll
        for (int ds = 0; ds < 4; ++ds) {
            int r = wave * 16 + (lane & 15);
            bf16x8 kf = *(const bf16x8*)((const char*)Klds + swz(r, 256, ds * 64 + (lane >> 4) * 16));
            #pragma unroll
            for (int ni = 0; ni < 4; ++ni)
                st[ni] = mfma16(kf, qf[ni][ds], st[ni]);
        }
        // P = exp2(s*SC2 - m2[k]), write bf16 to Plds (lane's 4 k contiguous)
        f32x4 mv = *(const f32x4*)&m2b[kc + wave * 16 + (lane >> 4) * 4];
        #pragma unroll
        for (int ni = 0; ni < 4; ++ni) {
            bf16x4 pk;
            pk[0] = (__bf16)EXP2F(st[ni][0] * SC2 - mv.x);
            pk[1] = (__bf16)EXP2F(st[ni][1] * SC2 - mv.y);
            pk[2] = (__bf16)EXP2F(st[ni][2] * SC2 - mv.z);
            pk[3] = (__bf16)EXP2F(st[ni][3] * SC2 - mv.w);
            int q = ni * 16 + (lane & 15);
            int colbyte = wave * 32 + (lane >> 4) * 8;
            *(bf16x4*)((char*)Plds + swz(q, 128, colbyte)) = pk;
        }
        __syncthreads();
        // PV: wave w owns v strip [w*32, w*32+32)
        #pragma unroll
        for (int ks = 0; ks < 2; ++ks) {
            bf16x8 pf[4], vf[2];
            #pragma unroll
            for (int mi = 0; mi < 4; ++mi) {
                int q = mi * 16 + (lane & 15);
                pf[mi] = *(const bf16x8*)((const char*)Plds + swz(q, 128, ks * 64 + (lane >> 4) * 16));
            }
            #pragma unroll
            for (int ni = 0; ni < 2; ++ni) {
                int v = wave * 32 + ni * 16 + (lane & 15);
                vf[ni] = *(const bf16x8*)((const char*)VTlds + swz(v, 128, ks * 64 + (lane >> 4) * 16));
            }
            #pragma unroll
            for (int mi = 0; mi < 4; ++mi)
                #pragma unroll
                for (int ni = 0; ni < 2; ++ni)
                    acc[mi][ni] = mfma16(pf[mi], vf[ni], acc[mi][ni]);
        }
    }
    // epilogue: fp32 atomic accumulate (KS blocks contribute per output)
    #pragma unroll
    for (int mi = 0; mi < 4; ++mi)
        #pragma unroll
        for (int ni = 0; ni < 2; ++ni)
            #pragma unroll
            for (int j = 0; j < 4; ++j) {
                int q = q0 + mi * 16 + (lane >> 4) * 4 + j;
                int v = wave * 32 + ni * 16 + (lane & 15);
                atomicAdd(&out[((size_t)b * L_ + q) * DH + v], acc[mi][ni][j]);
            }
}

// ---------------------------------------------------------------------------
extern "C" void kernel_launch(void* const* d_in, const int* in_sizes, int n_in,
                              void* d_out, int out_size, void* d_ws, size_t ws_size,
                              hipStream_t stream)
{
    const float* inq = (const float*)d_in[0];
    const float* ink = (const float*)d_in[1];
    const float* inv = (const float*)d_in[2];
    const float* Wq  = (const float*)d_in[3];
    const float* bq  = (const float*)d_in[4];
    const float* Wk  = (const float*)d_in[5];
    const float* bk  = (const float*)d_in[6];
    const float* Wv  = (const float*)d_in[7];
    const float* bv  = (const float*)d_in[8];
    float* out = (float*)d_out;

    const size_t nQKV = (size_t)B_ * L_ * DH;   // 2,097,152 elements
    const size_t nBL  = (size_t)B_ * L_;
    char* ws = (char*)d_ws;
    bf16_t* Q  = (bf16_t*)ws;
    bf16_t* K  = Q + nQKV;
    bf16_t* V  = K + nQKV;
    bf16_t* VT = V + nQKV;
    float*  M2    = (float*)(VT + nQKV);
    float*  Lsum  = M2 + nBL;
    float*  Mpart = Lsum + nBL;          // QS * B*L
    float*  Lpart = Mpart + QS * nBL;    // QS * B*L
    // Wb (3*128*1024 bf16 = 768 KB) aliases the VT region: Wb is only live
    // during wcvt+projd; VT is written by vt_kernel strictly after.
    bf16_t* Wbuf = VT;

    (void)hipMemsetAsync(out, 0, nQKV * sizeof(float), stream);
    wcvt_kernel<<<dim3(192), 256, 0, stream>>>(Wq, Wk, Wv, Wbuf);
    projd_kernel<<<dim3(512, 3), 128, 0, stream>>>(inq, ink, inv, Wbuf, bq, bk, bv, Q, K, V);
    stats_kernel<<<dim3(L_ / 64, B_, QS), 256, 0, stream>>>(Q, K, Mpart, Lpart);
    comb_kernel<<<dim3(nBL / 256), 256, 0, stream>>>(Mpart, Lpart, M2, Lsum);
    vt_kernel<<<dim3(L_ / 64, DH / 64, B_), 256, 0, stream>>>(V, Lsum, VT);
    pv_kernel<<<dim3(L_ / 64, B_, KS), 256, 0, stream>>>(Q, K, VT, M2, out);
}

// Round 9
// 186.219 us; speedup vs baseline: 1.4393x; 1.4145x over previous
//
#include <hip/hip_runtime.h>
#include <hip/hip_bf16.h>

#define B_  4
#define L_  4096
#define DM  1024
#define DH  128
#define KS  8     // k-split for pv
#define QS  8     // q-split for stats

// (1/sqrt(128)) * log2(e): softmax computed in exp2 domain (exact same function)
#define SC2 0.12752844f

typedef __bf16 bf16_t;
typedef __attribute__((ext_vector_type(8))) __bf16 bf16x8;
typedef __attribute__((ext_vector_type(4))) __bf16 bf16x4;
typedef __attribute__((ext_vector_type(4))) float f32x4;

#if __has_builtin(__builtin_amdgcn_exp2f)
#define EXP2F(x) __builtin_amdgcn_exp2f(x)
#else
#define EXP2F(x) exp2f(x)
#endif

__device__ __forceinline__ f32x4 mfma16(bf16x8 a, bf16x8 b, f32x4 c) {
    return __builtin_amdgcn_mfma_f32_16x16x32_bf16(a, b, c, 0, 0, 0);
}

// XOR swizzle on 16B slots within a row (row bytes must be 128 or 256)
__device__ __forceinline__ int swz(int row, int rowbytes, int colbyte) {
    int slot = colbyte >> 4;
    return row * rowbytes + (((slot ^ (row & 7)) << 4) | (colbyte & 15));
}

__device__ __forceinline__ bf16x8 cvt8v(f32x4 a, f32x4 b) {
    bf16x8 v;
    v[0] = (__bf16)a.x; v[1] = (__bf16)a.y; v[2] = (__bf16)a.z; v[3] = (__bf16)a.w;
    v[4] = (__bf16)b.x; v[5] = (__bf16)b.y; v[6] = (__bf16)b.z; v[7] = (__bf16)b.w;
    return v;
}

// async global->LDS, 16 B per lane. lds base must be wave-uniform; HW adds lane*16.
__device__ __forceinline__ void gload_lds16(const void* g, void* l) {
    __builtin_amdgcn_global_load_lds((const __attribute__((address_space(1))) void*)g,
                                     (__attribute__((address_space(3))) void*)l, 16, 0, 0);
}

// ---------------------------------------------------------------------------
// Kernel A0: W fp32 -> bf16 once.  Wb layout [3][DH][DM].  grid 192, block 256
// ---------------------------------------------------------------------------
__global__ __launch_bounds__(256) void wcvt_kernel(
    const float* __restrict__ Wq, const float* __restrict__ Wk, const float* __restrict__ Wv,
    bf16_t* __restrict__ Wb)
{
    int idx = (blockIdx.x * 256 + threadIdx.x) * 8;    // into [3][131072]
    int which = idx >> 17;
    int rem = idx & 131071;
    const float* W = which == 0 ? Wq : (which == 1 ? Wk : Wv);
    f32x4 a = *(const f32x4*)&W[rem];
    f32x4 b = *(const f32x4*)&W[rem + 4];
    *(bf16x8*)&Wb[idx] = cvt8v(a, b);
}

// ---------------------------------------------------------------------------
// Kernel A: projections with DEEP counted-vmcnt gload_lds pipeline (T3+T4).
// grid (256, 3), block 512 (8 waves, 2m x 4n).  BM=64, BN=128, 16 K-steps of 64.
// 4-deep LDS ring: X fp32 4x16KB + W bf16 4x16KB = 128 KB, 1 block/CU.
// Per iter: vmcnt(8) [tile t done, t+1/t+2 in flight] -> s_barrier ->
// issue tile t+3 -> compute t.  NEVER vmcnt(0) in steady state.
// Linear LDS dest + inverse-swizzled global source + swizzled read.
// ---------------------------------------------------------------------------
__global__ __launch_bounds__(512) void projp_kernel(
    const float* __restrict__ Xq, const float* __restrict__ Xk, const float* __restrict__ Xv,
    const bf16_t* __restrict__ Wb,
    const float* __restrict__ bq, const float* __restrict__ bk, const float* __restrict__ bv,
    bf16_t* __restrict__ Q, bf16_t* __restrict__ K, bf16_t* __restrict__ V)
{
    const int which = blockIdx.y;
    const float* X    = which == 0 ? Xq : (which == 1 ? Xk : Xv);
    const float* bias = which == 0 ? bq : (which == 1 ? bk : bv);
    bf16_t*      O    = which == 0 ? Q  : (which == 1 ? K  : V);
    const bf16_t* Wm  = Wb + (size_t)which * DH * DM;

    __shared__ float  Xlds[4][64 * 64];    // 4 x 16 KB, rows 256 B = 16 slots
    __shared__ bf16_t Wlds[4][128 * 64];   // 4 x 16 KB, rows 128 B = 8 slots

    const int tid  = threadIdx.x;
    const int lane = tid & 63;
    const int wave = tid >> 6;                 // 0..7
    const int wm = wave >> 2, wn = wave & 3;   // 2m x 4n: 32 rows x 32 h per wave
    const int i16 = lane & 15, g4 = lane >> 4;
    const int xr  = lane >> 4, xs = lane & 15; // X staging: 4 rows/KB
    const int wr8 = lane >> 3, ws8 = lane & 7; // W staging: 8 rows/KB
    const int row0 = blockIdx.x * 64;

    f32x4 acc[2][2] = {};

    // ---- stage tile t (64-K chunk): 4 gload_lds per thread (2 X + 2 W) ----
    #define STAGE(t)                                                                   \
        do {                                                                           \
            int kk_ = (t) * 64;                                                        \
            _Pragma("unroll")                                                          \
            for (int j_ = 0; j_ < 2; ++j_) {                                           \
                int c_ = j_ * 8 + wave;           /* KB chunk 0..15, 4 rows each */    \
                int r_ = c_ * 4 + xr;                                                  \
                gload_lds16(&X[(size_t)(row0 + r_) * DM + kk_ + ((xs ^ (r_ & 7)) << 2)],\
                            (char*)Xlds[(t) & 3] + c_ * 1024);                         \
            }                                                                          \
            _Pragma("unroll")                                                          \
            for (int j_ = 0; j_ < 2; ++j_) {                                           \
                int c_ = j_ * 8 + wave;           /* KB chunk 0..15, 8 rows each */    \
                int r_ = c_ * 8 + wr8;                                                 \
                gload_lds16(&Wm[(size_t)r_ * DM + kk_ + ((ws8 ^ (r_ & 7)) << 3)],      \
                            (char*)Wlds[(t) & 3] + c_ * 1024);                         \
            }                                                                          \
        } while (0)

    #define COMPUTE(t)                                                                 \
        do {                                                                           \
            const float*  xb_ = Xlds[(t) & 3];                                         \
            const bf16_t* wb_ = Wlds[(t) & 3];                                         \
            _Pragma("unroll")                                                          \
            for (int ks = 0; ks < 2; ++ks) {                                           \
                bf16x8 af[2], bfr[2];                                                  \
                _Pragma("unroll")                                                      \
                for (int mi = 0; mi < 2; ++mi) {                                       \
                    int r = wm * 32 + mi * 16 + i16;                                   \
                    int s0 = ks * 8 + g4 * 2;                                          \
                    f32x4 x0 = *(const f32x4*)((const char*)xb_ + r * 256 + ((s0 ^ (r & 7)) << 4));        \
                    f32x4 x1 = *(const f32x4*)((const char*)xb_ + r * 256 + (((s0 + 1) ^ (r & 7)) << 4));  \
                    af[mi] = cvt8v(x0, x1);                                            \
                }                                                                      \
                _Pragma("unroll")                                                      \
                for (int ni = 0; ni < 2; ++ni) {                                       \
                    int rw = wn * 32 + ni * 16 + i16;                                  \
                    int tt = ks * 4 + g4;                                              \
                    bfr[ni] = *(const bf16x8*)((const char*)wb_ + rw * 128 + ((tt ^ (rw & 7)) << 4));      \
                }                                                                      \
                _Pragma("unroll")                                                      \
                for (int mi = 0; mi < 2; ++mi)                                         \
                    _Pragma("unroll")                                                  \
                    for (int ni = 0; ni < 2; ++ni)                                     \
                        acc[mi][ni] = mfma16(af[mi], bfr[ni], acc[mi][ni]);            \
            }                                                                          \
        } while (0)

    // prologue: 3 tiles in flight
    STAGE(0); STAGE(1); STAGE(2);

    for (int t = 0; t < 16; ++t) {
        if (t < 14)       asm volatile("s_waitcnt vmcnt(8)" ::: "memory");
        else if (t == 14) asm volatile("s_waitcnt vmcnt(4)" ::: "memory");
        else              asm volatile("s_waitcnt vmcnt(0)" ::: "memory");
        __builtin_amdgcn_sched_barrier(0);
        __builtin_amdgcn_s_barrier();       // raw barrier: does NOT drain vmcnt
        __builtin_amdgcn_sched_barrier(0);
        if (t + 3 < 16) STAGE(t + 3);       // writes buf (t-1)&3: consumed last iter
        COMPUTE(t);
    }
    #undef STAGE
    #undef COMPUTE

    // epilogue: + bias, write bf16.  C/D: col=lane&15, row=(lane>>4)*4+j
    #pragma unroll
    for (int ni = 0; ni < 2; ++ni) {
        int h = wn * 32 + ni * 16 + i16;
        float bb = bias[h];
        #pragma unroll
        for (int mi = 0; mi < 2; ++mi)
            #pragma unroll
            for (int j = 0; j < 4; ++j) {
                int r = row0 + wm * 32 + mi * 16 + g4 * 4 + j;
                O[(size_t)r * DH + h] = (__bf16)(acc[mi][ni][j] + bb);
            }
    }
}

// ---------------------------------------------------------------------------
// Kernel B: column-softmax partial stats over a q-range of L/QS.
// grid (64, B, QS), block 256.  Per block: 64 k-columns, L/QS q rows.
// ---------------------------------------------------------------------------
__global__ __launch_bounds__(256) void stats_kernel(
    const bf16_t* __restrict__ Q, const bf16_t* __restrict__ K,
    float* __restrict__ Mpart, float* __restrict__ Lpart)
{
    const int b  = blockIdx.y;
    const int k0 = blockIdx.x * 64;
    const int qs = blockIdx.z;
    const int tid = threadIdx.x, lane = tid & 63, wave = tid >> 6;

    __shared__ bf16_t Klds[64 * 128];    // 16 KB, rows 256 B swizzled
    __shared__ bf16_t Qlds[128 * 128];   // 32 KB

    const bf16_t* Kb = K + ((size_t)b * L_ + k0) * DH;
    #pragma unroll
    for (int it = 0; it < 4; ++it) {
        int id = it * 256 + tid;
        int r = id >> 4, s = id & 15;
        bf16x8 x = *(const bf16x8*)&Kb[(size_t)r * DH + s * 8];
        *(bf16x8*)((char*)Klds + swz(r, 256, s * 16)) = x;
    }
    __syncthreads();
    // resident K fragments: [ni = 16-col block][d-slice]
    bf16x8 kfr[4][4];
    #pragma unroll
    for (int ni = 0; ni < 4; ++ni)
        #pragma unroll
        for (int ds = 0; ds < 4; ++ds) {
            int r = ni * 16 + (lane & 15);
            kfr[ni][ds] = *(const bf16x8*)((const char*)Klds + swz(r, 256, ds * 64 + (lane >> 4) * 16));
        }

    float mrun[4], lrun[4];
    #pragma unroll
    for (int ni = 0; ni < 4; ++ni) { mrun[ni] = -1e30f; lrun[ni] = 0.f; }

    const bf16_t* Qb = Q + (size_t)b * L_ * DH;
    const int qbase = qs * (L_ / QS);
    for (int q0 = qbase; q0 < qbase + L_ / QS; q0 += 128) {
        __syncthreads();
        #pragma unroll
        for (int it = 0; it < 8; ++it) {
            int id = it * 256 + tid;
            int r = id >> 4, s = id & 15;
            bf16x8 x = *(const bf16x8*)&Qb[(size_t)(q0 + r) * DH + s * 8];
            *(bf16x8*)((char*)Qlds + swz(r, 256, s * 16)) = x;
        }
        __syncthreads();
        // wave w: q rows [w*32, w*32+32), all 64 k
        f32x4 st[2][4] = {};
        #pragma unroll
        for (int mi = 0; mi < 2; ++mi)
            #pragma unroll
            for (int ds = 0; ds < 4; ++ds) {
                int r = wave * 32 + mi * 16 + (lane & 15);
                bf16x8 af = *(const bf16x8*)((const char*)Qlds + swz(r, 256, ds * 64 + (lane >> 4) * 16));
                #pragma unroll
                for (int ni = 0; ni < 4; ++ni)
                    st[mi][ni] = mfma16(af, kfr[ni][ds], st[mi][ni]);
            }
        // online per-column update (col k = lane&15 within ni block)
        #pragma unroll
        for (int ni = 0; ni < 4; ++ni) {
            float cm = -1e30f;
            #pragma unroll
            for (int mi = 0; mi < 2; ++mi)
                #pragma unroll
                for (int j = 0; j < 4; ++j) cm = fmaxf(cm, st[mi][ni][j]);
            cm *= SC2;
            cm = fmaxf(cm, __shfl_xor(cm, 16, 64));
            cm = fmaxf(cm, __shfl_xor(cm, 32, 64));
            float mnew = fmaxf(mrun[ni], cm);
            float p = 0.f;
            #pragma unroll
            for (int mi = 0; mi < 2; ++mi)
                #pragma unroll
                for (int j = 0; j < 4; ++j)
                    p += EXP2F(st[mi][ni][j] * SC2 - mnew);
            p += __shfl_xor(p, 16, 64);
            p += __shfl_xor(p, 32, 64);
            lrun[ni] = lrun[ni] * EXP2F(mrun[ni] - mnew) + p;
            mrun[ni] = mnew;
        }
    }
    // cross-wave combine (each wave covered a disjoint q subset)
    __syncthreads();
    float* redm = (float*)Klds;       // reuse: 4*64 floats
    float* redl = redm + 256;
    if (lane < 16) {
        #pragma unroll
        for (int ni = 0; ni < 4; ++ni) {
            redm[wave * 64 + ni * 16 + lane] = mrun[ni];
            redl[wave * 64 + ni * 16 + lane] = lrun[ni];
        }
    }
    __syncthreads();
    if (tid < 64) {
        float m0 = redm[tid], m1 = redm[64 + tid], m2v = redm[128 + tid], m3 = redm[192 + tid];
        float mt = fmaxf(fmaxf(m0, m1), fmaxf(m2v, m3));
        float lt = redl[tid]       * EXP2F(m0 - mt) + redl[64 + tid]  * EXP2F(m1 - mt)
                 + redl[128 + tid] * EXP2F(m2v - mt) + redl[192 + tid] * EXP2F(m3 - mt);
        Mpart[((size_t)qs * B_ + b) * L_ + k0 + tid] = mt;
        Lpart[((size_t)qs * B_ + b) * L_ + k0 + tid] = lt;
    }
}

// ---------------------------------------------------------------------------
// Kernel B2: combine QS partial stats -> M2, Lsum.  grid (B*L/256), block 256
// ---------------------------------------------------------------------------
__global__ __launch_bounds__(256) void comb_kernel(
    const float* __restrict__ Mpart, const float* __restrict__ Lpart,
    float* __restrict__ M2, float* __restrict__ Lsum)
{
    const size_t i = (size_t)blockIdx.x * 256 + threadIdx.x;
    const size_t N = (size_t)B_ * L_;
    float m = -1e30f;
    #pragma unroll
    for (int qs = 0; qs < QS; ++qs) m = fmaxf(m, Mpart[qs * N + i]);
    float l = 0.f;
    #pragma unroll
    for (int qs = 0; qs < QS; ++qs) l += Lpart[qs * N + i] * EXP2F(Mpart[qs * N + i] - m);
    M2[i] = m;
    Lsum[i] = l;
}

// ---------------------------------------------------------------------------
// Kernel C: VT[b][v][k] = V[b][k][v] / l[b][k]   (transpose + scale)
// grid (64, 2, 4), block 256
// ---------------------------------------------------------------------------
__global__ __launch_bounds__(256) void vt_kernel(
    const bf16_t* __restrict__ V, const float* __restrict__ Lsum, bf16_t* __restrict__ VT)
{
    const int b = blockIdx.z, v0 = blockIdx.y * 64, k0 = blockIdx.x * 64;
    __shared__ bf16_t tile[64][72];
    const int tid = threadIdx.x;
    const bf16_t* Vb = V + ((size_t)b * L_ + k0) * DH + v0;
    #pragma unroll
    for (int it = 0; it < 2; ++it) {
        int id = it * 256 + tid;
        int r = id >> 3, s = id & 7;
        bf16x8 x = *(const bf16x8*)&Vb[(size_t)r * DH + s * 8];
        *(bf16x8*)&tile[r][s * 8] = x;
    }
    __syncthreads();
    const int lane = tid & 63, wave = tid >> 6;
    float rl = 1.0f / Lsum[(size_t)b * L_ + k0 + lane];
    bf16_t* VTb = VT + ((size_t)b * DH + v0) * L_ + k0;
    #pragma unroll
    for (int i = 0; i < 16; ++i) {
        int v = wave * 16 + i;
        float x = (float)tile[lane][v];
        VTb[(size_t)v * L_ + lane] = (__bf16)(x * rl);
    }
}

// ---------------------------------------------------------------------------
// Kernel D: H[q,v] += sum_{k in range} exp2(s*SC2 - m2[k]) * VT[v][k]
// grid (64, B, KS), block 256 (4 waves).  q-block 64, k-range L/KS, chunks 64.
// Partial k-sums are additive (1/l folded into VT) -> fp32 atomicAdd to out.
// ---------------------------------------------------------------------------
__global__ __launch_bounds__(256) void pv_kernel(
    const bf16_t* __restrict__ Q, const bf16_t* __restrict__ K,
    const bf16_t* __restrict__ VT, const float* __restrict__ M2,
    float* __restrict__ out)
{
    const int b = blockIdx.y;
    const int q0 = blockIdx.x * 64;
    const int tid = threadIdx.x, lane = tid & 63, wave = tid >> 6;

    __shared__ bf16_t QPlds[64 * 128];   // 16 KB: Q staging, then P tile (first 8 KB)
    __shared__ bf16_t Klds[64 * 128];    // 16 KB
    __shared__ bf16_t VTlds[128 * 64];   // 16 KB, rows 128 B

    const bf16_t* Qb = Q + ((size_t)b * L_ + q0) * DH;
    #pragma unroll
    for (int it = 0; it < 4; ++it) {
        int id = it * 256 + tid;
        int r = id >> 4, s = id & 15;
        bf16x8 x = *(const bf16x8*)&Qb[(size_t)r * DH + s * 8];
        *(bf16x8*)((char*)QPlds + swz(r, 256, s * 16)) = x;
    }
    __syncthreads();
    // resident Q fragments (B-operand of S^T): [ni = q 16-block][d-slice]
    bf16x8 qf[4][4];
    #pragma unroll
    for (int ni = 0; ni < 4; ++ni)
        #pragma unroll
        for (int ds = 0; ds < 4; ++ds) {
            int r = ni * 16 + (lane & 15);
            qf[ni][ds] = *(const bf16x8*)((const char*)QPlds + swz(r, 256, ds * 64 + (lane >> 4) * 16));
        }

    f32x4 acc[4][2] = {};
    const float*  m2b = M2 + (size_t)b * L_;
    const bf16_t* Kb  = K  + (size_t)b * L_ * DH;
    const bf16_t* VTb = VT + (size_t)b * DH * L_;
    bf16_t* Plds = QPlds;                // alias: safe after qf loads + barrier

    const int kbase = blockIdx.z * (L_ / KS);
    for (int kc = kbase; kc < kbase + L_ / KS; kc += 64) {
        __syncthreads();
        // stage K chunk [64 k][128 d]
        #pragma unroll
        for (int it = 0; it < 4; ++it) {
            int id = it * 256 + tid;
            int r = id >> 4, s = id & 15;
            bf16x8 x = *(const bf16x8*)&Kb[(size_t)(kc + r) * DH + s * 8];
            *(bf16x8*)((char*)Klds + swz(r, 256, s * 16)) = x;
        }
        // stage VT chunk [128 v][64 k]
        #pragma unroll
        for (int it = 0; it < 4; ++it) {
            int id = it * 256 + tid;
            int r = id >> 3, s = id & 7;
            bf16x8 x = *(const bf16x8*)&VTb[(size_t)r * L_ + kc + s * 8];
            *(bf16x8*)((char*)VTlds + swz(r, 128, s * 16)) = x;
        }
        __syncthreads();
        // S^T tile: wave w owns k rows [w*16, w*16+16), all 64 q
        f32x4 st[4] = {};
        #pragma unroll
        for (int ds = 0; ds < 4; ++ds) {
            int r = wave * 16 + (lane & 15);
            bf16x8 kf = *(const bf16x8*)((const char*)Klds + swz(r, 256, ds * 64 + (lane >> 4) * 16));
            #pragma unroll
            for (int ni = 0; ni < 4; ++ni)
                st[ni] = mfma16(kf, qf[ni][ds], st[ni]);
        }
        // P = exp2(s*SC2 - m2[k]), write bf16 to Plds (lane's 4 k contiguous)
        f32x4 mv = *(const f32x4*)&m2b[kc + wave * 16 + (lane >> 4) * 4];
        #pragma unroll
        for (int ni = 0; ni < 4; ++ni) {
            bf16x4 pk;
            pk[0] = (__bf16)EXP2F(st[ni][0] * SC2 - mv.x);
            pk[1] = (__bf16)EXP2F(st[ni][1] * SC2 - mv.y);
            pk[2] = (__bf16)EXP2F(st[ni][2] * SC2 - mv.z);
            pk[3] = (__bf16)EXP2F(st[ni][3] * SC2 - mv.w);
            int q = ni * 16 + (lane & 15);
            int colbyte = wave * 32 + (lane >> 4) * 8;
            *(bf16x4*)((char*)Plds + swz(q, 128, colbyte)) = pk;
        }
        __syncthreads();
        // PV: wave w owns v strip [w*32, w*32+32)
        #pragma unroll
        for (int ks = 0; ks < 2; ++ks) {
            bf16x8 pf[4], vf[2];
            #pragma unroll
            for (int mi = 0; mi < 4; ++mi) {
                int q = mi * 16 + (lane & 15);
                pf[mi] = *(const bf16x8*)((const char*)Plds + swz(q, 128, ks * 64 + (lane >> 4) * 16));
            }
            #pragma unroll
            for (int ni = 0; ni < 2; ++ni) {
                int v = wave * 32 + ni * 16 + (lane & 15);
                vf[ni] = *(const bf16x8*)((const char*)VTlds + swz(v, 128, ks * 64 + (lane >> 4) * 16));
            }
            #pragma unroll
            for (int mi = 0; mi < 4; ++mi)
                #pragma unroll
                for (int ni = 0; ni < 2; ++ni)
                    acc[mi][ni] = mfma16(pf[mi], vf[ni], acc[mi][ni]);
        }
    }
    // epilogue: fp32 atomic accumulate (KS blocks contribute per output)
    #pragma unroll
    for (int mi = 0; mi < 4; ++mi)
        #pragma unroll
        for (int ni = 0; ni < 2; ++ni)
            #pragma unroll
            for (int j = 0; j < 4; ++j) {
                int q = q0 + mi * 16 + (lane >> 4) * 4 + j;
                int v = wave * 32 + ni * 16 + (lane & 15);
                atomicAdd(&out[((size_t)b * L_ + q) * DH + v], acc[mi][ni][j]);
            }
}

// ---------------------------------------------------------------------------
extern "C" void kernel_launch(void* const* d_in, const int* in_sizes, int n_in,
                              void* d_out, int out_size, void* d_ws, size_t ws_size,
                              hipStream_t stream)
{
    const float* inq = (const float*)d_in[0];
    const float* ink = (const float*)d_in[1];
    const float* inv = (const float*)d_in[2];
    const float* Wq  = (const float*)d_in[3];
    const float* bq  = (const float*)d_in[4];
    const float* Wk  = (const float*)d_in[5];
    const float* bk  = (const float*)d_in[6];
    const float* Wv  = (const float*)d_in[7];
    const float* bv  = (const float*)d_in[8];
    float* out = (float*)d_out;

    const size_t nQKV = (size_t)B_ * L_ * DH;   // 2,097,152 elements
    const size_t nBL  = (size_t)B_ * L_;
    char* ws = (char*)d_ws;
    bf16_t* Q  = (bf16_t*)ws;
    bf16_t* K  = Q + nQKV;
    bf16_t* V  = K + nQKV;
    bf16_t* VT = V + nQKV;
    float*  M2    = (float*)(VT + nQKV);
    float*  Lsum  = M2 + nBL;
    float*  Mpart = Lsum + nBL;          // QS * B*L
    float*  Lpart = Mpart + QS * nBL;    // QS * B*L
    // Wb (3*128*1024 bf16 = 768 KB) aliases the VT region: Wb is only live
    // during wcvt+projp; VT is written by vt_kernel strictly after.
    bf16_t* Wbuf = VT;

    (void)hipMemsetAsync(out, 0, nQKV * sizeof(float), stream);
    wcvt_kernel<<<dim3(192), 256, 0, stream>>>(Wq, Wk, Wv, Wbuf);
    projp_kernel<<<dim3(256, 3), 512, 0, stream>>>(inq, ink, inv, Wbuf, bq, bk, bv, Q, K, V);
    stats_kernel<<<dim3(L_ / 64, B_, QS), 256, 0, stream>>>(Q, K, Mpart, Lpart);
    comb_kernel<<<dim3(nBL / 256), 256, 0, stream>>>(Mpart, Lpart, M2, Lsum);
    vt_kernel<<<dim3(L_ / 64, DH / 64, B_), 256, 0, stream>>>(V, Lsum, VT);
    pv_kernel<<<dim3(L_ / 64, B_, KS), 256, 0, stream>>>(Q, K, VT, M2, out);
}

// Round 10
// 185.158 us; speedup vs baseline: 1.4475x; 1.0057x over previous
//
#include <hip/hip_runtime.h>
#include <hip/hip_bf16.h>

#define B_  4
#define L_  4096
#define DM  1024
#define DH  128
#define KS  8     // k-split for pv
#define QS  8     // q-split for stats

// (1/sqrt(128)) * log2(e): softmax computed in exp2 domain (exact same function)
#define SC2 0.12752844f

typedef __bf16 bf16_t;
typedef __attribute__((ext_vector_type(8))) __bf16 bf16x8;
typedef __attribute__((ext_vector_type(4))) __bf16 bf16x4;
typedef __attribute__((ext_vector_type(4))) float f32x4;

#if __has_builtin(__builtin_amdgcn_exp2f)
#define EXP2F(x) __builtin_amdgcn_exp2f(x)
#else
#define EXP2F(x) exp2f(x)
#endif

__device__ __forceinline__ f32x4 mfma16(bf16x8 a, bf16x8 b, f32x4 c) {
    return __builtin_amdgcn_mfma_f32_16x16x32_bf16(a, b, c, 0, 0, 0);
}

// XOR swizzle on 16B slots within a row (row bytes must be 128 or 256)
__device__ __forceinline__ int swz(int row, int rowbytes, int colbyte) {
    int slot = colbyte >> 4;
    return row * rowbytes + (((slot ^ (row & 7)) << 4) | (colbyte & 15));
}

__device__ __forceinline__ bf16x8 cvt8v(f32x4 a, f32x4 b) {
    bf16x8 v;
    v[0] = (__bf16)a.x; v[1] = (__bf16)a.y; v[2] = (__bf16)a.z; v[3] = (__bf16)a.w;
    v[4] = (__bf16)b.x; v[5] = (__bf16)b.y; v[6] = (__bf16)b.z; v[7] = (__bf16)b.w;
    return v;
}

// async global->LDS, 16 B per lane. lds base must be wave-uniform; HW adds lane*16.
__device__ __forceinline__ void gload_lds16(const void* g, void* l) {
    __builtin_amdgcn_global_load_lds((const __attribute__((address_space(1))) void*)g,
                                     (__attribute__((address_space(3))) void*)l, 16, 0, 0);
}

// ---------------------------------------------------------------------------
// Kernel A0: W fp32 -> bf16 once.  Wb layout [3][DH][DM].  grid 192, block 256
// ---------------------------------------------------------------------------
__global__ __launch_bounds__(256) void wcvt_kernel(
    const float* __restrict__ Wq, const float* __restrict__ Wk, const float* __restrict__ Wv,
    bf16_t* __restrict__ Wb)
{
    int idx = (blockIdx.x * 256 + threadIdx.x) * 8;    // into [3][131072]
    int which = idx >> 17;
    int rem = idx & 131071;
    const float* W = which == 0 ? Wq : (which == 1 ? Wk : Wv);
    f32x4 a = *(const f32x4*)&W[rem];
    f32x4 b = *(const f32x4*)&W[rem + 4];
    *(bf16x8*)&Wb[idx] = cvt8v(a, b);
}

// ---------------------------------------------------------------------------
// Kernel A: CONTIGUOUS-PANEL projections.  grid (512, 3), block 256 (4 waves).
// BM=32 rows x FULL K=1024: each block stages one contiguous 128-KB X panel
// (each wave sweeps 8 complete 4-KB rows -> chip-wide linear sweep like the
// 6.3 TB/s copy ubench, no strided column-slices) to bf16 swizzled LDS (64 KB).
// Then 16 K-chunks: W (L2-hot bf16) gload_lds'd into 16-KB buffer, 2 barriers
// per chunk.  LDS 80 KB -> 2 blocks/CU: one block streams while the other
// computes (m114 wave-level overlap).
// ---------------------------------------------------------------------------
__global__ __launch_bounds__(256) void projc_kernel(
    const float* __restrict__ Xq, const float* __restrict__ Xk, const float* __restrict__ Xv,
    const bf16_t* __restrict__ Wb,
    const float* __restrict__ bq, const float* __restrict__ bk, const float* __restrict__ bv,
    bf16_t* __restrict__ Q, bf16_t* __restrict__ K, bf16_t* __restrict__ V)
{
    const int which = blockIdx.y;
    const float* X    = which == 0 ? Xq : (which == 1 ? Xk : Xv);
    const float* bias = which == 0 ? bq : (which == 1 ? bk : bv);
    bf16_t*      O    = which == 0 ? Q  : (which == 1 ? K  : V);
    const bf16_t* Wm  = Wb + (size_t)which * DH * DM;

    __shared__ bf16_t Xp[32 * 1024];    // 64 KB: [32 rows][1024 bf16], 128 16-B slots/row
    __shared__ bf16_t Wc[128 * 64];     // 16 KB: one 64-K W chunk, rows 128 B

    const int tid  = threadIdx.x;
    const int lane = tid & 63;
    const int wave = tid >> 6;            // 0..3, n-split only
    const int i16 = lane & 15, g4 = lane >> 4;
    const int row0 = blockIdx.x * 32;

    // ---- stage X panel: wave w sweeps rows w*8..w*8+8 CONTIGUOUSLY ----
    #pragma unroll
    for (int p = 0; p < 8; ++p) {
        int r = wave * 8 + p;
        const float* rowp = &X[(size_t)(row0 + r) * DM];
        #pragma unroll
        for (int h = 0; h < 2; ++h) {
            // 64 lanes x 32 B = one contiguous 2-KB half-row per issue
            f32x4 a = *(const f32x4*)&rowp[h * 512 + lane * 8];
            f32x4 b = *(const f32x4*)&rowp[h * 512 + lane * 8 + 4];
            int s = h * 64 + lane;                       // 16-B slot 0..127
            *(bf16x8*)((char*)Xp + r * 2048 + ((s ^ (r & 7)) << 4)) = cvt8v(a, b);
        }
    }

    f32x4 acc[2][2] = {};

    for (int t = 0; t < 16; ++t) {
        // stage W chunk [128 h][64 k] at col t*64 via gload_lds (prev compute done)
        #pragma unroll
        for (int j = 0; j < 4; ++j) {
            int c = j * 4 + wave;            // KB chunk 0..15, 8 rows each
            int r = c * 8 + (lane >> 3);
            int s = lane & 7;
            gload_lds16(&Wm[(size_t)r * DM + t * 64 + ((s ^ (r & 7)) << 3)],
                        (char*)Wc + c * 1024);
        }
        __syncthreads();   // X (t==0) + W chunk visible

        #pragma unroll
        for (int ks = 0; ks < 2; ++ks) {
            int q = t * 8 + ks * 4 + g4;     // global 16-B slot in X row
            bf16x8 af[2], wf[2];
            #pragma unroll
            for (int mi = 0; mi < 2; ++mi) {
                int r = mi * 16 + i16;
                af[mi] = *(const bf16x8*)((const char*)Xp + r * 2048 + ((q ^ (r & 7)) << 4));
            }
            #pragma unroll
            for (int ni = 0; ni < 2; ++ni) {
                int rw = wave * 32 + ni * 16 + i16;
                int tt = ks * 4 + g4;
                wf[ni] = *(const bf16x8*)((const char*)Wc + rw * 128 + ((tt ^ (rw & 7)) << 4));
            }
            #pragma unroll
            for (int mi = 0; mi < 2; ++mi)
                #pragma unroll
                for (int ni = 0; ni < 2; ++ni)
                    acc[mi][ni] = mfma16(af[mi], wf[ni], acc[mi][ni]);
        }
        __syncthreads();   // compute done before next chunk overwrites Wc
    }

    // epilogue: + bias, write bf16.  C/D: col=lane&15, row=(lane>>4)*4+j
    #pragma unroll
    for (int ni = 0; ni < 2; ++ni) {
        int h = wave * 32 + ni * 16 + i16;
        float bb = bias[h];
        #pragma unroll
        for (int mi = 0; mi < 2; ++mi)
            #pragma unroll
            for (int j = 0; j < 4; ++j) {
                int r = row0 + mi * 16 + g4 * 4 + j;
                O[(size_t)r * DH + h] = (__bf16)(acc[mi][ni][j] + bb);
            }
    }
}

// ---------------------------------------------------------------------------
// Kernel B: column-softmax partial stats over a q-range of L/QS.
// grid (64, B, QS), block 256.  Per block: 64 k-columns, L/QS q rows.
// ---------------------------------------------------------------------------
__global__ __launch_bounds__(256) void stats_kernel(
    const bf16_t* __restrict__ Q, const bf16_t* __restrict__ K,
    float* __restrict__ Mpart, float* __restrict__ Lpart)
{
    const int b  = blockIdx.y;
    const int k0 = blockIdx.x * 64;
    const int qs = blockIdx.z;
    const int tid = threadIdx.x, lane = tid & 63, wave = tid >> 6;

    __shared__ bf16_t Klds[64 * 128];    // 16 KB, rows 256 B swizzled
    __shared__ bf16_t Qlds[128 * 128];   // 32 KB

    const bf16_t* Kb = K + ((size_t)b * L_ + k0) * DH;
    #pragma unroll
    for (int it = 0; it < 4; ++it) {
        int id = it * 256 + tid;
        int r = id >> 4, s = id & 15;
        bf16x8 x = *(const bf16x8*)&Kb[(size_t)r * DH + s * 8];
        *(bf16x8*)((char*)Klds + swz(r, 256, s * 16)) = x;
    }
    __syncthreads();
    // resident K fragments: [ni = 16-col block][d-slice]
    bf16x8 kfr[4][4];
    #pragma unroll
    for (int ni = 0; ni < 4; ++ni)
        #pragma unroll
        for (int ds = 0; ds < 4; ++ds) {
            int r = ni * 16 + (lane & 15);
            kfr[ni][ds] = *(const bf16x8*)((const char*)Klds + swz(r, 256, ds * 64 + (lane >> 4) * 16));
        }

    float mrun[4], lrun[4];
    #pragma unroll
    for (int ni = 0; ni < 4; ++ni) { mrun[ni] = -1e30f; lrun[ni] = 0.f; }

    const bf16_t* Qb = Q + (size_t)b * L_ * DH;
    const int qbase = qs * (L_ / QS);
    for (int q0 = qbase; q0 < qbase + L_ / QS; q0 += 128) {
        __syncthreads();
        #pragma unroll
        for (int it = 0; it < 8; ++it) {
            int id = it * 256 + tid;
            int r = id >> 4, s = id & 15;
            bf16x8 x = *(const bf16x8*)&Qb[(size_t)(q0 + r) * DH + s * 8];
            *(bf16x8*)((char*)Qlds + swz(r, 256, s * 16)) = x;
        }
        __syncthreads();
        // wave w: q rows [w*32, w*32+32), all 64 k
        f32x4 st[2][4] = {};
        #pragma unroll
        for (int mi = 0; mi < 2; ++mi)
            #pragma unroll
            for (int ds = 0; ds < 4; ++ds) {
                int r = wave * 32 + mi * 16 + (lane & 15);
                bf16x8 af = *(const bf16x8*)((const char*)Qlds + swz(r, 256, ds * 64 + (lane >> 4) * 16));
                #pragma unroll
                for (int ni = 0; ni < 4; ++ni)
                    st[mi][ni] = mfma16(af, kfr[ni][ds], st[mi][ni]);
            }
        // online per-column update (col k = lane&15 within ni block)
        #pragma unroll
        for (int ni = 0; ni < 4; ++ni) {
            float cm = -1e30f;
            #pragma unroll
            for (int mi = 0; mi < 2; ++mi)
                #pragma unroll
                for (int j = 0; j < 4; ++j) cm = fmaxf(cm, st[mi][ni][j]);
            cm *= SC2;
            cm = fmaxf(cm, __shfl_xor(cm, 16, 64));
            cm = fmaxf(cm, __shfl_xor(cm, 32, 64));
            float mnew = fmaxf(mrun[ni], cm);
            float p = 0.f;
            #pragma unroll
            for (int mi = 0; mi < 2; ++mi)
                #pragma unroll
                for (int j = 0; j < 4; ++j)
                    p += EXP2F(st[mi][ni][j] * SC2 - mnew);
            p += __shfl_xor(p, 16, 64);
            p += __shfl_xor(p, 32, 64);
            lrun[ni] = lrun[ni] * EXP2F(mrun[ni] - mnew) + p;
            mrun[ni] = mnew;
        }
    }
    // cross-wave combine (each wave covered a disjoint q subset)
    __syncthreads();
    float* redm = (float*)Klds;       // reuse: 4*64 floats
    float* redl = redm + 256;
    if (lane < 16) {
        #pragma unroll
        for (int ni = 0; ni < 4; ++ni) {
            redm[wave * 64 + ni * 16 + lane] = mrun[ni];
            redl[wave * 64 + ni * 16 + lane] = lrun[ni];
        }
    }
    __syncthreads();
    if (tid < 64) {
        float m0 = redm[tid], m1 = redm[64 + tid], m2v = redm[128 + tid], m3 = redm[192 + tid];
        float mt = fmaxf(fmaxf(m0, m1), fmaxf(m2v, m3));
        float lt = redl[tid]       * EXP2F(m0 - mt) + redl[64 + tid]  * EXP2F(m1 - mt)
                 + redl[128 + tid] * EXP2F(m2v - mt) + redl[192 + tid] * EXP2F(m3 - mt);
        Mpart[((size_t)qs * B_ + b) * L_ + k0 + tid] = mt;
        Lpart[((size_t)qs * B_ + b) * L_ + k0 + tid] = lt;
    }
}

// ---------------------------------------------------------------------------
// Kernel B2: combine QS partial stats -> M2, Lsum.  grid (B*L/256), block 256
// ---------------------------------------------------------------------------
__global__ __launch_bounds__(256) void comb_kernel(
    const float* __restrict__ Mpart, const float* __restrict__ Lpart,
    float* __restrict__ M2, float* __restrict__ Lsum)
{
    const size_t i = (size_t)blockIdx.x * 256 + threadIdx.x;
    const size_t N = (size_t)B_ * L_;
    float m = -1e30f;
    #pragma unroll
    for (int qs = 0; qs < QS; ++qs) m = fmaxf(m, Mpart[qs * N + i]);
    float l = 0.f;
    #pragma unroll
    for (int qs = 0; qs < QS; ++qs) l += Lpart[qs * N + i] * EXP2F(Mpart[qs * N + i] - m);
    M2[i] = m;
    Lsum[i] = l;
}

// ---------------------------------------------------------------------------
// Kernel C: VT[b][v][k] = V[b][k][v] / l[b][k]   (transpose + scale)
// grid (64, 2, 4), block 256
// ---------------------------------------------------------------------------
__global__ __launch_bounds__(256) void vt_kernel(
    const bf16_t* __restrict__ V, const float* __restrict__ Lsum, bf16_t* __restrict__ VT)
{
    const int b = blockIdx.z, v0 = blockIdx.y * 64, k0 = blockIdx.x * 64;
    __shared__ bf16_t tile[64][72];
    const int tid = threadIdx.x;
    const bf16_t* Vb = V + ((size_t)b * L_ + k0) * DH + v0;
    #pragma unroll
    for (int it = 0; it < 2; ++it) {
        int id = it * 256 + tid;
        int r = id >> 3, s = id & 7;
        bf16x8 x = *(const bf16x8*)&Vb[(size_t)r * DH + s * 8];
        *(bf16x8*)&tile[r][s * 8] = x;
    }
    __syncthreads();
    const int lane = tid & 63, wave = tid >> 6;
    float rl = 1.0f / Lsum[(size_t)b * L_ + k0 + lane];
    bf16_t* VTb = VT + ((size_t)b * DH + v0) * L_ + k0;
    #pragma unroll
    for (int i = 0; i < 16; ++i) {
        int v = wave * 16 + i;
        float x = (float)tile[lane][v];
        VTb[(size_t)v * L_ + lane] = (__bf16)(x * rl);
    }
}

// ---------------------------------------------------------------------------
// Kernel D: H[q,v] += sum_{k in range} exp2(s*SC2 - m2[k]) * VT[v][k]
// grid (64, B, KS), block 256 (4 waves).  q-block 64, k-range L/KS, chunks 64.
// Partial k-sums are additive (1/l folded into VT) -> fp32 atomicAdd to out.
// ---------------------------------------------------------------------------
__global__ __launch_bounds__(256) void pv_kernel(
    const bf16_t* __restrict__ Q, const bf16_t* __restrict__ K,
    const bf16_t* __restrict__ VT, const float* __restrict__ M2,
    float* __restrict__ out)
{
    const int b = blockIdx.y;
    const int q0 = blockIdx.x * 64;
    const int tid = threadIdx.x, lane = tid & 63, wave = tid >> 6;

    __shared__ bf16_t QPlds[64 * 128];   // 16 KB: Q staging, then P tile (first 8 KB)
    __shared__ bf16_t Klds[64 * 128];    // 16 KB
    __shared__ bf16_t VTlds[128 * 64];   // 16 KB, rows 128 B

    const bf16_t* Qb = Q + ((size_t)b * L_ + q0) * DH;
    #pragma unroll
    for (int it = 0; it < 4; ++it) {
        int id = it * 256 + tid;
        int r = id >> 4, s = id & 15;
        bf16x8 x = *(const bf16x8*)&Qb[(size_t)r * DH + s * 8];
        *(bf16x8*)((char*)QPlds + swz(r, 256, s * 16)) = x;
    }
    __syncthreads();
    // resident Q fragments (B-operand of S^T): [ni = q 16-block][d-slice]
    bf16x8 qf[4][4];
    #pragma unroll
    for (int ni = 0; ni < 4; ++ni)
        #pragma unroll
        for (int ds = 0; ds < 4; ++ds) {
            int r = ni * 16 + (lane & 15);
            qf[ni][ds] = *(const bf16x8*)((const char*)QPlds + swz(r, 256, ds * 64 + (lane >> 4) * 16));
        }

    f32x4 acc[4][2] = {};
    const float*  m2b = M2 + (size_t)b * L_;
    const bf16_t* Kb  = K  + (size_t)b * L_ * DH;
    const bf16_t* VTb = VT + (size_t)b * DH * L_;
    bf16_t* Plds = QPlds;                // alias: safe after qf loads + barrier

    const int kbase = blockIdx.z * (L_ / KS);
    for (int kc = kbase; kc < kbase + L_ / KS; kc += 64) {
        __syncthreads();
        // stage K chunk [64 k][128 d]
        #pragma unroll
        for (int it = 0; it < 4; ++it) {
            int id = it * 256 + tid;
            int r = id >> 4, s = id & 15;
            bf16x8 x = *(const bf16x8*)&Kb[(size_t)(kc + r) * DH + s * 8];
            *(bf16x8*)((char*)Klds + swz(r, 256, s * 16)) = x;
        }
        // stage VT chunk [128 v][64 k]
        #pragma unroll
        for (int it = 0; it < 4; ++it) {
            int id = it * 256 + tid;
            int r = id >> 3, s = id & 7;
            bf16x8 x = *(const bf16x8*)&VTb[(size_t)r * L_ + kc + s * 8];
            *(bf16x8*)((char*)VTlds + swz(r, 128, s * 16)) = x;
        }
        __syncthreads();
        // S^T tile: wave w owns k rows [w*16, w*16+16), all 64 q
        f32x4 st[4] = {};
        #pragma unroll
        for (int ds = 0; ds < 4; ++ds) {
            int r = wave * 16 + (lane & 15);
            bf16x8 kf = *(const bf16x8*)((const char*)Klds + swz(r, 256, ds * 64 + (lane >> 4) * 16));
            #pragma unroll
            for (int ni = 0; ni < 4; ++ni)
                st[ni] = mfma16(kf, qf[ni][ds], st[ni]);
        }
        // P = exp2(s*SC2 - m2[k]), write bf16 to Plds (lane's 4 k contiguous)
        f32x4 mv = *(const f32x4*)&m2b[kc + wave * 16 + (lane >> 4) * 4];
        #pragma unroll
        for (int ni = 0; ni < 4; ++ni) {
            bf16x4 pk;
            pk[0] = (__bf16)EXP2F(st[ni][0] * SC2 - mv.x);
            pk[1] = (__bf16)EXP2F(st[ni][1] * SC2 - mv.y);
            pk[2] = (__bf16)EXP2F(st[ni][2] * SC2 - mv.z);
            pk[3] = (__bf16)EXP2F(st[ni][3] * SC2 - mv.w);
            int q = ni * 16 + (lane & 15);
            int colbyte = wave * 32 + (lane >> 4) * 8;
            *(bf16x4*)((char*)Plds + swz(q, 128, colbyte)) = pk;
        }
        __syncthreads();
        // PV: wave w owns v strip [w*32, w*32+32)
        #pragma unroll
        for (int ks = 0; ks < 2; ++ks) {
            bf16x8 pf[4], vf[2];
            #pragma unroll
            for (int mi = 0; mi < 4; ++mi) {
                int q = mi * 16 + (lane & 15);
                pf[mi] = *(const bf16x8*)((const char*)Plds + swz(q, 128, ks * 64 + (lane >> 4) * 16));
            }
            #pragma unroll
            for (int ni = 0; ni < 2; ++ni) {
                int v = wave * 32 + ni * 16 + (lane & 15);
                vf[ni] = *(const bf16x8*)((const char*)VTlds + swz(v, 128, ks * 64 + (lane >> 4) * 16));
            }
            #pragma unroll
            for (int mi = 0; mi < 4; ++mi)
                #pragma unroll
                for (int ni = 0; ni < 2; ++ni)
                    acc[mi][ni] = mfma16(pf[mi], vf[ni], acc[mi][ni]);
        }
    }
    // epilogue: fp32 atomic accumulate (KS blocks contribute per output)
    #pragma unroll
    for (int mi = 0; mi < 4; ++mi)
        #pragma unroll
        for (int ni = 0; ni < 2; ++ni)
            #pragma unroll
            for (int j = 0; j < 4; ++j) {
                int q = q0 + mi * 16 + (lane >> 4) * 4 + j;
                int v = wave * 32 + ni * 16 + (lane & 15);
                atomicAdd(&out[((size_t)b * L_ + q) * DH + v], acc[mi][ni][j]);
            }
}

// ---------------------------------------------------------------------------
extern "C" void kernel_launch(void* const* d_in, const int* in_sizes, int n_in,
                              void* d_out, int out_size, void* d_ws, size_t ws_size,
                              hipStream_t stream)
{
    const float* inq = (const float*)d_in[0];
    const float* ink = (const float*)d_in[1];
    const float* inv = (const float*)d_in[2];
    const float* Wq  = (const float*)d_in[3];
    const float* bq  = (const float*)d_in[4];
    const float* Wk  = (const float*)d_in[5];
    const float* bk  = (const float*)d_in[6];
    const float* Wv  = (const float*)d_in[7];
    const float* bv  = (const float*)d_in[8];
    float* out = (float*)d_out;

    const size_t nQKV = (size_t)B_ * L_ * DH;   // 2,097,152 elements
    const size_t nBL  = (size_t)B_ * L_;
    char* ws = (char*)d_ws;
    bf16_t* Q  = (bf16_t*)ws;
    bf16_t* K  = Q + nQKV;
    bf16_t* V  = K + nQKV;
    bf16_t* VT = V + nQKV;
    float*  M2    = (float*)(VT + nQKV);
    float*  Lsum  = M2 + nBL;
    float*  Mpart = Lsum + nBL;          // QS * B*L
    float*  Lpart = Mpart + QS * nBL;    // QS * B*L
    // Wb (3*128*1024 bf16 = 768 KB) aliases the VT region: Wb is only live
    // during wcvt+projc; VT is written by vt_kernel strictly after.
    bf16_t* Wbuf = VT;

    (void)hipMemsetAsync(out, 0, nQKV * sizeof(float), stream);
    wcvt_kernel<<<dim3(192), 256, 0, stream>>>(Wq, Wk, Wv, Wbuf);
    projc_kernel<<<dim3(512, 3), 256, 0, stream>>>(inq, ink, inv, Wbuf, bq, bk, bv, Q, K, V);
    stats_kernel<<<dim3(L_ / 64, B_, QS), 256, 0, stream>>>(Q, K, Mpart, Lpart);
    comb_kernel<<<dim3(nBL / 256), 256, 0, stream>>>(Mpart, Lpart, M2, Lsum);
    vt_kernel<<<dim3(L_ / 64, DH / 64, B_), 256, 0, stream>>>(V, Lsum, VT);
    pv_kernel<<<dim3(L_ / 64, B_, KS), 256, 0, stream>>>(Q, K, VT, M2, out);
}